// Round 5
// baseline (1129.777 us; speedup 1.0000x reference)
//
#include <hip/hip_runtime.h>
#include <stdint.h>

// Hashgrid encoder (instant-NGP style), L=16 levels, D=3, C=2, H=16, S=1.
// Table layout (global entry index space, float2 entries):
//   [0 .. 524288)          -> ext_embeddings
//   [524288 .. 7131240)    -> own_embeddings (global - 524288)
// Levels 0-2: dense indexing (side = 16*2^l + 1), index provably < hashmap
// size, so the reference's `% hm` is a no-op. Levels 3-15: spatial hash,
// hashmap size 2^19 -> mask 0x7FFFF. Level 3's global range [315496,839784)
// straddles the ext/own split at 524288 -> branchless pointer select.

__device__ __constant__ const uint32_t kOffs[16] = {
    0u, 4920u, 40864u, 315496u, 839784u, 1364072u, 1888360u, 2412648u,
    2936936u, 3461224u, 3985512u, 4509800u, 5034088u, 5558376u, 6082664u, 6606952u
};

#define HASH_ENTRIES 524288u
#define HASH_MASK    (HASH_ENTRIES - 1u)
#define P1 2654435761u
#define P2 805459861u

typedef float floatx4 __attribute__((ext_vector_type(4)));  // clang vector: valid for nontemporal builtins

__global__ __launch_bounds__(256) void grid_encode_kernel(
    const float* __restrict__ xyz,
    const float2* __restrict__ ext,   // 524288 entries
    const float2* __restrict__ own,   // remaining entries
    float* __restrict__ out,
    int B)
{
    const int b = blockIdx.x * 256 + threadIdx.x;
    if (b >= B) return;

    const float x = xyz[3 * b + 0];
    const float y = xyz[3 * b + 1];
    const float z = xyz[3 * b + 2];
    const float x01 = (x + 1.0f) * 0.5f;
    const float y01 = (y + 1.0f) * 0.5f;
    const float z01 = (z + 1.0f) * 0.5f;

    float res[32];

#pragma unroll
    for (int l = 0; l < 16; ++l) {
        const float scale = (float)((16u << l) - 1u);   // exact in fp32 (< 2^24)
        const float px = x01 * scale + 0.5f;
        const float py = y01 * scale + 0.5f;
        const float pz = z01 * scale + 0.5f;
        const float fxf = floorf(px), fyf = floorf(py), fzf = floorf(pz);
        const float tx = px - fxf, ty = py - fyf, tz = pz - fzf;
        const uint32_t x0 = (uint32_t)(int)fxf;
        const uint32_t y0 = (uint32_t)(int)fyf;
        const uint32_t z0 = (uint32_t)(int)fzf;

        // Dense level constants (compile-time after unroll)
        const uint32_t side = (16u << l) + 1u;
        const uint32_t s2 = side * side;
        const uint32_t dense_base = x0 + y0 * side + z0 * s2;

        // Hash level precomputes (PRIMES[0] == 1)
        const uint32_t hx0 = x0,       hx1 = x0 + 1u;
        const uint32_t hy0 = y0 * P1,  hy1 = (y0 + 1u) * P1;
        const uint32_t hz0 = z0 * P2,  hz1 = (z0 + 1u) * P2;

        float r0 = 0.0f, r1 = 0.0f;
#pragma unroll
        for (int i = 0; i < 8; ++i) {
            uint32_t gi;
            if (l < 3) {
                gi = dense_base + (uint32_t)(i & 1)
                                + (uint32_t)((i >> 1) & 1) * side
                                + (uint32_t)((i >> 2) & 1) * s2;
            } else {
                gi = (((i & 1) ? hx1 : hx0) ^
                      ((i & 2) ? hy1 : hy0) ^
                      ((i & 4) ? hz1 : hz0)) & HASH_MASK;
            }

            float2 f;
            if (l < 3) {
                f = ext[kOffs[l] + gi];
            } else if (l == 3) {
                // level 3 straddles the ext/own boundary at 524288
                const uint32_t g = gi + 315496u;
                const float2* p = (g < HASH_ENTRIES) ? (ext + g)
                                                     : (own + (g - HASH_ENTRIES));
                f = *p;
            } else {
                f = own[(kOffs[l] - HASH_ENTRIES) + gi];
            }

            const float wi = ((i & 1) ? tx : 1.0f - tx)
                           * ((i & 2) ? ty : 1.0f - ty)
                           * ((i & 4) ? tz : 1.0f - tz);
            r0 += wi * f.x;
            r1 += wi * f.y;
        }
        res[2 * l + 0] = r0;
        res[2 * l + 1] = r1;
    }

    // 8x 16B nontemporal stores (streaming output; keep L2/L3 for the table)
    floatx4* o4 = (floatx4*)(out + (size_t)b * 32);
#pragma unroll
    for (int k = 0; k < 8; ++k) {
        floatx4 v = { res[4 * k + 0], res[4 * k + 1],
                      res[4 * k + 2], res[4 * k + 3] };
        __builtin_nontemporal_store(v, &o4[k]);
    }
}

extern "C" void kernel_launch(void* const* d_in, const int* in_sizes, int n_in,
                              void* d_out, int out_size, void* d_ws, size_t ws_size,
                              hipStream_t stream) {
    const float*  xyz = (const float*)d_in[0];
    const float2* ext = (const float2*)d_in[1];
    const float2* own = (const float2*)d_in[2];
    float* out = (float*)d_out;
    const int B = in_sizes[0] / 3;
    const int grid = (B + 255) / 256;
    grid_encode_kernel<<<grid, 256, 0, stream>>>(xyz, ext, own, out, B);
}

// Round 6
// 1053.764 us; speedup vs baseline: 1.0721x; 1.0721x over previous
//
#include <hip/hip_runtime.h>
#include <stdint.h>

// Hashgrid encoder (instant-NGP style), L=16 levels, D=3, C=2, H=16, S=1.
// Table layout (global entry index space, float2 entries):
//   [0 .. 524288)          -> ext_embeddings
//   [524288 .. 7131240)    -> own_embeddings (global - 524288)
// Levels 0-2 dense (index provably < hashmap size, % is a no-op);
// levels 3-15 spatial hash, hm = 2^19 -> mask. Level 3's global range
// [315496,839784) straddles the ext/own split -> branchless pointer select.
//
// R5 structure: 4 level-groups; per group ISSUE all 32 gathers into regs
// before consuming (MLP was the R4 bottleneck: VGPR=36 -> ~6 loads in
// flight -> 3.85 TB/s latency-limited).

__device__ __constant__ const uint32_t kOffs[16] = {
    0u, 4920u, 40864u, 315496u, 839784u, 1364072u, 1888360u, 2412648u,
    2936936u, 3461224u, 3985512u, 4509800u, 5034088u, 5558376u, 6082664u, 6606952u
};

#define HASH_ENTRIES 524288u
#define HASH_MASK    (HASH_ENTRIES - 1u)
#define P1 2654435761u
#define P2 805459861u

typedef float floatx4 __attribute__((ext_vector_type(4)));

__global__ __launch_bounds__(256, 4) void grid_encode_kernel(
    const float* __restrict__ xyz,
    const float2* __restrict__ ext,   // 524288 entries
    const float2* __restrict__ own,   // remaining entries
    float* __restrict__ out,
    int B)
{
    const int b = blockIdx.x * 256 + threadIdx.x;
    if (b >= B) return;

    const float x01 = (xyz[3 * b + 0] + 1.0f) * 0.5f;
    const float y01 = (xyz[3 * b + 1] + 1.0f) * 0.5f;
    const float z01 = (xyz[3 * b + 2] + 1.0f) * 0.5f;

    float* ob = out + (size_t)b * 32;

#pragma unroll
    for (int g = 0; g < 4; ++g) {
        float2 f[32];               // all indices compile-time after unroll
        float tx[4], ty[4], tz[4];

        // ---- Phase 1: compute indices and ISSUE all 32 loads ----
#pragma unroll
        for (int j = 0; j < 4; ++j) {
            const int l = g * 4 + j;
            const float scale = (float)((16u << l) - 1u);   // exact in fp32
            const float px = x01 * scale + 0.5f;
            const float py = y01 * scale + 0.5f;
            const float pz = z01 * scale + 0.5f;
            const float fxf = floorf(px), fyf = floorf(py), fzf = floorf(pz);
            tx[j] = px - fxf; ty[j] = py - fyf; tz[j] = pz - fzf;
            const uint32_t x0 = (uint32_t)(int)fxf;
            const uint32_t y0 = (uint32_t)(int)fyf;
            const uint32_t z0 = (uint32_t)(int)fzf;

            const uint32_t side = (16u << l) + 1u;   // dense levels only
            const uint32_t s2 = side * side;
            const uint32_t dense_base = x0 + y0 * side + z0 * s2;

            const uint32_t hx0 = x0,       hx1 = x0 + 1u;   // PRIMES[0]==1
            const uint32_t hy0 = y0 * P1,  hy1 = (y0 + 1u) * P1;
            const uint32_t hz0 = z0 * P2,  hz1 = (z0 + 1u) * P2;

#pragma unroll
            for (int i = 0; i < 8; ++i) {
                if (l < 3) {
                    const uint32_t gi = dense_base + (uint32_t)(i & 1)
                                      + (uint32_t)((i >> 1) & 1) * side
                                      + (uint32_t)((i >> 2) & 1) * s2;
                    f[j * 8 + i] = ext[kOffs[l] + gi];
                } else {
                    const uint32_t gi = (((i & 1) ? hx1 : hx0) ^
                                         ((i & 2) ? hy1 : hy0) ^
                                         ((i & 4) ? hz1 : hz0)) & HASH_MASK;
                    if (l == 3) {
                        // straddles the ext/own boundary at 524288
                        const uint32_t gg = gi + 315496u;
                        const float2* p = (gg < HASH_ENTRIES)
                                            ? (ext + gg)
                                            : (own + (gg - HASH_ENTRIES));
                        f[j * 8 + i] = *p;
                    } else {
                        f[j * 8 + i] = own[(kOffs[l] - HASH_ENTRIES) + gi];
                    }
                }
            }
        }

        // ---- Phase 2: accumulate the 4 levels of this group ----
        float r[8];
#pragma unroll
        for (int j = 0; j < 4; ++j) {
            float r0 = 0.0f, r1 = 0.0f;
#pragma unroll
            for (int i = 0; i < 8; ++i) {
                const float wi = ((i & 1) ? tx[j] : 1.0f - tx[j])
                               * ((i & 2) ? ty[j] : 1.0f - ty[j])
                               * ((i & 4) ? tz[j] : 1.0f - tz[j]);
                r0 += wi * f[j * 8 + i].x;
                r1 += wi * f[j * 8 + i].y;
            }
            r[2 * j + 0] = r0;
            r[2 * j + 1] = r1;
        }

        // ---- Phase 3: store this group's 8 floats (plain stores; let L2
        //      write-combine the per-lane 128B-stride pattern) ----
        floatx4 v0 = { r[0], r[1], r[2], r[3] };
        floatx4 v1 = { r[4], r[5], r[6], r[7] };
        *(floatx4*)(ob + g * 8 + 0) = v0;
        *(floatx4*)(ob + g * 8 + 4) = v1;
    }
}

extern "C" void kernel_launch(void* const* d_in, const int* in_sizes, int n_in,
                              void* d_out, int out_size, void* d_ws, size_t ws_size,
                              hipStream_t stream) {
    const float*  xyz = (const float*)d_in[0];
    const float2* ext = (const float2*)d_in[1];
    const float2* own = (const float2*)d_in[2];
    float* out = (float*)d_out;
    const int B = in_sizes[0] / 3;
    const int grid = (B + 255) / 256;
    grid_encode_kernel<<<grid, 256, 0, stream>>>(xyz, ext, own, out, B);
}

// Round 7
// 879.131 us; speedup vs baseline: 1.2851x; 1.1986x over previous
//
#include <hip/hip_runtime.h>
#include <stdint.h>

// Hashgrid encoder, L=16, D=3, C=2, H=16, S=1.
// R7: XCD-rotated level schedule. R6 showed a ~3.7 TB/s random-64B fabric
// ceiling: each XCD's 4MB L2 sees all 13 hash tables (52MB) -> ~8% hit.
// Rotating the level processing order per XCD (start level = 2*(bid&7))
// puts each XCD on a DIFFERENT single 4MB table at any phase -> per-XCD
// working set == L2 size -> gathers become L2 hits instead of fabric trips.
// Everything else (per-thread all-16-levels, accumulate, coalesced region
// stores) is unchanged from R6.

__device__ __constant__ uint32_t kOffs[16] = {
    0u, 4920u, 40864u, 315496u, 839784u, 1364072u, 1888360u, 2412648u,
    2936936u, 3461224u, 3985512u, 4509800u, 5034088u, 5558376u, 6082664u, 6606952u
};

#define HASH_ENTRIES 524288u
#define HASH_MASK    (HASH_ENTRIES - 1u)
#define P1 2654435761u
#define P2 805459861u

typedef float floatx2 __attribute__((ext_vector_type(2)));

__global__ __launch_bounds__(256) void grid_encode_kernel(
    const float* __restrict__ xyz,
    const float2* __restrict__ ext,   // 524288 entries
    const float2* __restrict__ own,   // remaining entries
    float* __restrict__ out,
    int B)
{
    const int b = blockIdx.x * 256 + threadIdx.x;
    if (b >= B) return;

    // XCD id (round-robin dispatch assumption); level rotation = 2*xcd.
    const uint32_t rot = ((uint32_t)blockIdx.x & 7u) * 2u;

    const float x01 = (xyz[3 * b + 0] + 1.0f) * 0.5f;
    const float y01 = (xyz[3 * b + 1] + 1.0f) * 0.5f;
    const float z01 = (xyz[3 * b + 2] + 1.0f) * 0.5f;

    float rs[32];   // indexed by compile-time s only (no scratch spill)

#pragma unroll
    for (int s = 0; s < 16; ++s) {
        const uint32_t l = ((uint32_t)s + rot) & 15u;   // uniform per block

        const float scale = (float)((16u << l) - 1u);   // exact in fp32
        const float px = x01 * scale + 0.5f;
        const float py = y01 * scale + 0.5f;
        const float pz = z01 * scale + 0.5f;
        const float fxf = floorf(px), fyf = floorf(py), fzf = floorf(pz);
        const float tx = px - fxf, ty = py - fyf, tz = pz - fzf;
        const uint32_t x0 = (uint32_t)(int)fxf;
        const uint32_t y0 = (uint32_t)(int)fyf;
        const uint32_t z0 = (uint32_t)(int)fzf;

        float2 f[8];
        if (l < 3u) {
            // dense: index provably < hashmap size (and whole level in ext)
            const uint32_t side = (16u << l) + 1u;
            const uint32_t s2 = side * side;
            const uint32_t base = kOffs[l] + x0 + y0 * side + z0 * s2;
#pragma unroll
            for (int i = 0; i < 8; ++i) {
                f[i] = ext[base + (uint32_t)(i & 1)
                               + (uint32_t)((i >> 1) & 1) * side
                               + (uint32_t)((i >> 2) & 1) * s2];
            }
        } else {
            const uint32_t hx0 = x0,       hx1 = x0 + 1u;   // PRIMES[0]==1
            const uint32_t hy0 = y0 * P1,  hy1 = (y0 + 1u) * P1;
            const uint32_t hz0 = z0 * P2,  hz1 = (z0 + 1u) * P2;
            if (l == 3u) {
                // level 3 straddles the ext/own boundary at 524288
#pragma unroll
                for (int i = 0; i < 8; ++i) {
                    const uint32_t gi = (((i & 1) ? hx1 : hx0) ^
                                         ((i & 2) ? hy1 : hy0) ^
                                         ((i & 4) ? hz1 : hz0)) & HASH_MASK;
                    const uint32_t gg = gi + 315496u;
                    const float2* p = (gg < HASH_ENTRIES)
                                        ? (ext + gg)
                                        : (own + (gg - HASH_ENTRIES));
                    f[i] = *p;
                }
            } else {
                const float2* tbl = own + (kOffs[l] - HASH_ENTRIES);
#pragma unroll
                for (int i = 0; i < 8; ++i) {
                    const uint32_t gi = (((i & 1) ? hx1 : hx0) ^
                                         ((i & 2) ? hy1 : hy0) ^
                                         ((i & 4) ? hz1 : hz0)) & HASH_MASK;
                    f[i] = tbl[gi];
                }
            }
        }

        float r0 = 0.0f, r1 = 0.0f;
#pragma unroll
        for (int i = 0; i < 8; ++i) {
            const float wi = ((i & 1) ? tx : 1.0f - tx)
                           * ((i & 2) ? ty : 1.0f - ty)
                           * ((i & 4) ? tz : 1.0f - tz);
            r0 += wi * f[i].x;
            r1 += wi * f[i].y;
        }
        rs[2 * s + 0] = r0;
        rs[2 * s + 1] = r1;
    }

    // Stores: iteration s produced level l=(s+rot)&15 -> float offset
    // (2s+2rot)&31. 16 uniform-rotated 8B stores, issued back-to-back so
    // the wave's 128B/point region write-combines into full lines in L2.
    float* ob = out + (size_t)b * 32;
#pragma unroll
    for (int s = 0; s < 16; ++s) {
        const uint32_t off = (2u * (uint32_t)s + 2u * rot) & 31u;
        floatx2 v = { rs[2 * s + 0], rs[2 * s + 1] };
        *(floatx2*)(ob + off) = v;
    }
}

extern "C" void kernel_launch(void* const* d_in, const int* in_sizes, int n_in,
                              void* d_out, int out_size, void* d_ws, size_t ws_size,
                              hipStream_t stream) {
    const float*  xyz = (const float*)d_in[0];
    const float2* ext = (const float2*)d_in[1];
    const float2* own = (const float2*)d_in[2];
    float* out = (float*)d_out;
    const int B = in_sizes[0] / 3;
    const int grid = (B + 255) / 256;
    grid_encode_kernel<<<grid, 256, 0, stream>>>(xyz, ext, own, out, B);
}